// Round 8
// baseline (22644.031 us; speedup 1.0000x reference)
//
#include <hip/hip_runtime.h>

typedef unsigned int   uint32;
typedef unsigned short u16;
typedef unsigned long long u64;
typedef __bf16 bf16x8 __attribute__((ext_vector_type(8)));
typedef u16    ushort8 __attribute__((ext_vector_type(8)));
typedef float  f32x4  __attribute__((ext_vector_type(4)));

// ---------------------------------------------------------------------------
// Exact 3-way bf16 split (truncation): v == bf(a)+bf(b)+bf(c) EXACTLY for all
// normal fp32 (24 mantissa bits = 8+8+8; each subtraction is exact).
// ---------------------------------------------------------------------------
struct Split3 { u16 a, b, c; };
__device__ __forceinline__ Split3 split3(float v) {
  uint32 u  = __float_as_uint(v);
  u16 s1    = (u16)(u >> 16);
  float r1  = v - __uint_as_float(u & 0xFFFF0000u);   // exact
  uint32 u2 = __float_as_uint(r1);
  u16 s2    = (u16)(u2 >> 16);
  float r2  = r1 - __uint_as_float(u2 & 0xFFFF0000u); // exact
  u16 s3    = (u16)(__float_as_uint(r2) >> 16);       // r2 fits bf16 exactly
  return {s1, s2, s3};
}

// ===========================================================================
// K1: xin = x @ W_in + b_in   (M=32768, N=1024, K=1024) in fp32-emulated
// bf16x3 MFMA (6 products). Tile 128x128, BK=32, 256 thr (4 waves), grid 2048.
// ===========================================================================
__global__ __launch_bounds__(256, 2) void gemm6(const float* __restrict__ x,
                                                const float* __restrict__ win,
                                                const float* __restrict__ bin,
                                                float* __restrict__ out) {
  __shared__ u16 As[3][128 * 40];  // [split][m][k], pad 40 -> 2-way banks (free)
  __shared__ u16 Bs[3][128 * 40];  // [split][n][k]
  const int bm = blockIdx.x >> 3, bn = blockIdx.x & 7;
  const int tid = threadIdx.x;
  const int w = tid >> 6, lane = tid & 63, quad = lane >> 4, li = lane & 15;
  const int row0 = bm * 128, col0 = bn * 128;

  f32x4 acc[2][8];
#pragma unroll
  for (int a = 0; a < 2; ++a)
#pragma unroll
    for (int b = 0; b < 8; ++b) acc[a][b] = (f32x4){0.f, 0.f, 0.f, 0.f};

  const int bc = tid & 127;       // B: this thread's local col
  const int bkh = tid >> 7;       // B: k-half (0/1) -> k = bkh*16 + kk

  for (int kb = 0; kb < 32; ++kb) {
    __syncthreads();
    // ---- stage A: 128m x 32k fp32 -> 3 split planes ----
#pragma unroll
    for (int i = 0; i < 4; ++i) {
      int idx = i * 256 + tid;                 // 0..1023 float4s
      int m = idx >> 3, kq = (idx & 7) * 4;
      float4 v = *(const float4*)&x[(size_t)(row0 + m) * 1024 + kb * 32 + kq];
      Split3 s0 = split3(v.x), s1 = split3(v.y), s2 = split3(v.z), s3 = split3(v.w);
      *(uint2*)&As[0][m * 40 + kq] = make_uint2((uint32)s0.a | ((uint32)s1.a << 16),
                                                (uint32)s2.a | ((uint32)s3.a << 16));
      *(uint2*)&As[1][m * 40 + kq] = make_uint2((uint32)s0.b | ((uint32)s1.b << 16),
                                                (uint32)s2.b | ((uint32)s3.b << 16));
      *(uint2*)&As[2][m * 40 + kq] = make_uint2((uint32)s0.c | ((uint32)s1.c << 16),
                                                (uint32)s2.c | ((uint32)s3.c << 16));
    }
    // ---- stage B: 32k x 128n, thread reads 16 k's of one col (coalesced) ----
    {
      u16 t1[16], t2[16], t3[16];
#pragma unroll
      for (int kk = 0; kk < 16; ++kk) {
        float v = win[(size_t)(kb * 32 + bkh * 16 + kk) * 1024 + col0 + bc];
        Split3 s = split3(v);
        t1[kk] = s.a; t2[kk] = s.b; t3[kk] = s.c;
      }
#pragma unroll
      for (int q = 0; q < 4; ++q) {
        int off = bc * 40 + bkh * 16 + q * 4;
        *(uint2*)&Bs[0][off] = make_uint2((uint32)t1[q*4] | ((uint32)t1[q*4+1] << 16),
                                          (uint32)t1[q*4+2] | ((uint32)t1[q*4+3] << 16));
        *(uint2*)&Bs[1][off] = make_uint2((uint32)t2[q*4] | ((uint32)t2[q*4+1] << 16),
                                          (uint32)t2[q*4+2] | ((uint32)t2[q*4+3] << 16));
        *(uint2*)&Bs[2][off] = make_uint2((uint32)t3[q*4] | ((uint32)t3[q*4+1] << 16),
                                          (uint32)t3[q*4+2] | ((uint32)t3[q*4+3] << 16));
      }
    }
    __syncthreads();
    // ---- compute: 2 m-tiles x 8 n-tiles x 6 split-products ----
    bf16x8 af[2][3];
#pragma unroll
    for (int mi = 0; mi < 2; ++mi)
#pragma unroll
      for (int s = 0; s < 3; ++s)
        af[mi][s] = *(const bf16x8*)&As[s][(w * 32 + mi * 16 + li) * 40 + quad * 8];
#pragma unroll
    for (int nf = 0; nf < 8; ++nf) {
      bf16x8 b1 = *(const bf16x8*)&Bs[0][(nf * 16 + li) * 40 + quad * 8];
      bf16x8 b2 = *(const bf16x8*)&Bs[1][(nf * 16 + li) * 40 + quad * 8];
      bf16x8 b3 = *(const bf16x8*)&Bs[2][(nf * 16 + li) * 40 + quad * 8];
#pragma unroll
      for (int mi = 0; mi < 2; ++mi) {
        f32x4 c = acc[mi][nf];
        c = __builtin_amdgcn_mfma_f32_16x16x32_bf16(af[mi][2], b1, c, 0, 0, 0); // a3*b1
        c = __builtin_amdgcn_mfma_f32_16x16x32_bf16(af[mi][1], b2, c, 0, 0, 0); // a2*b2
        c = __builtin_amdgcn_mfma_f32_16x16x32_bf16(af[mi][0], b3, c, 0, 0, 0); // a1*b3
        c = __builtin_amdgcn_mfma_f32_16x16x32_bf16(af[mi][1], b1, c, 0, 0, 0); // a2*b1
        c = __builtin_amdgcn_mfma_f32_16x16x32_bf16(af[mi][0], b2, c, 0, 0, 0); // a1*b2
        c = __builtin_amdgcn_mfma_f32_16x16x32_bf16(af[mi][0], b1, c, 0, 0, 0); // a1*b1
        acc[mi][nf] = c;
      }
    }
  }
  // ---- epilogue: + bias (no relu here; scan applies relu per step) ----
#pragma unroll
  for (int mi = 0; mi < 2; ++mi)
#pragma unroll
    for (int nf = 0; nf < 8; ++nf) {
      int gcol = col0 + nf * 16 + li;
      float bias = bin[gcol];
#pragma unroll
      for (int r = 0; r < 4; ++r) {
        int grow = row0 + w * 32 + mi * 16 + quad * 4 + r;
        out[(size_t)grow * 1024 + gcol] = acc[mi][nf][r] + bias;
      }
    }
}

// ===========================================================================
// K2 v8: persistent recurrence, 32 WGs x 512 thr, PER-WAVE producer waits.
// Key insight: wave w consumes k-slice [p*512 + w*64, +64) = exactly the
// output of producer WG w (pass 0) and producer w+8 (pass 1). So instead of
// the WG-wide wait-for-all-16 + barriered staging, each wave:
//   polls its OWN 2 flags -> stages its OWN 24 u64 (both passes, one flight)
//   into wave-private LDS -> computes (no cross-wave barriers).
// Early producers' stage+compute overlaps waiting for stragglers.
// Barriers/step: 6 -> 2 (red reduction + publish drain).
//
// FROZEN CORE (do not touch): rolled compute p-loop (#pragma unroll 1) with
// runtime-p-indexed wfr (scratch-resident; register promotion via static p
// MISCOMPILES deterministically — v2-v5, absmax 5.5). Acquire-per-poll.
// Flag/publish protocol and MFMA accumulation order: v7 verbatim.
// ===========================================================================
#define WROW 72   // 64 k + 8 pad u16 (matches v7's 2-way/8-way bank profile)

__global__ __launch_bounds__(512, 1) void rnn_scan(const float* __restrict__ whh,
                                                   float* __restrict__ out,
                                                   void* ws) {
  uint32* ctr  = (uint32*)ws;                  // flags: ctr[g*32 + m], m<16
  u16*    hbuf = (u16*)((char*)ws + 256);
  u64*    hb64 = (u64*)hbuf;
  uint32* hb32 = (uint32*)hbuf;

  const int wg = blockIdx.x, g = wg & 1, m = wg >> 1;   // m in 0..15
  const int tid = threadIdx.x;
  const int w = tid >> 6, lane = tid & 63, quad = lane >> 4, li = lane & 15;
  const int b0 = g * 16, f0 = m * 64;

  __shared__ u16  hT[8][2][3][16 * WROW];  // [wave][pass][split][b][k64+pad], 108 KB
  __shared__ float red[8][1024];           // per-wave partials [b*64+col], 32 KB

  // ---- W_hh -> 48 B-frags: wfr[p][kc][nt][s]; k = p*512+w*64+kc*32+quad*8+j
  bf16x8 wfr[2][2][4][3];
#pragma unroll
  for (int p = 0; p < 2; ++p)
#pragma unroll
    for (int kc = 0; kc < 2; ++kc)
#pragma unroll
      for (int nt = 0; nt < 4; ++nt) {
        ushort8 t1, t2, t3;
#pragma unroll
        for (int j = 0; j < 8; ++j) {
          float v = whh[(size_t)(p * 512 + w * 64 + kc * 32 + quad * 8 + j) * 1024
                        + f0 + nt * 16 + li];
          Split3 s = split3(v);
          t1[j] = s.a; t2[j] = s.b; t3[j] = s.c;
        }
        wfr[p][kc][nt][0] = __builtin_bit_cast(bf16x8, t1);
        wfr[p][kc][nt][1] = __builtin_bit_cast(bf16x8, t2);
        wfr[p][kc][nt][2] = __builtin_bit_cast(bf16x8, t3);
      }

  // epilogue ownership: thread -> (batch eb, col pair ecp), 512 thr cover 16x64
  const int eb = tid >> 5, ecp = (tid & 31) * 2;

#pragma unroll 1
  for (int t = 0; t < 1024; ++t) {
    f32x4 acc[4];
#pragma unroll
    for (int nt = 0; nt < 4; ++nt) acc[nt] = (f32x4){0.f, 0.f, 0.f, 0.f};

    if (t > 0) {
      // ---- per-wave poll: lane0 -> producer w (pass0), lane1 -> w+8 (pass1) ----
      if (lane < 2) {
        const uint32 fidx = (uint32)(g * 32 + w + lane * 8);
        while (__hip_atomic_load(&ctr[fidx], __ATOMIC_ACQUIRE,
                                 __HIP_MEMORY_SCOPE_AGENT) < (uint32)t)
          __builtin_amdgcn_s_sleep(2);
      }
      // wave reconverged; its producers' data is visible (acquire above).

      const int par = (t - 1) & 1;
      const size_t base64 = (size_t)par * 24576 + (size_t)g * 12288;

      // ---- stage this wave's 2 slices (24 u64/lane, single flight) ----
#pragma unroll
      for (int i = 0; i < 24; ++i) {
        const int p = i / 12, ii = i % 12;
        int c = ii * 64 + lane;              // 0..767 per pass
        int s = c >> 8, b = (c >> 4) & 15, k4 = c & 15;
        u64 v = __hip_atomic_load(
            &hb64[base64 + s * 4096 + b * 256 + p * 128 + w * 16 + k4],
            __ATOMIC_RELAXED, __HIP_MEMORY_SCOPE_AGENT);
        *(uint2*)&hT[w][p][s][b * WROW + k4 * 4] =
            make_uint2((uint32)v, (uint32)(v >> 32));
      }
      // (wave-private region: compiler's lgkmcnt/vmcnt tracking suffices; no barrier)

      // ---- compute: rolled p (FROZEN — wfr must stay runtime-p-indexed) ----
#pragma unroll 1
      for (int p = 0; p < 2; ++p) {
#pragma unroll
        for (int kc = 0; kc < 2; ++kc) {
          const int ao = li * WROW + kc * 32 + quad * 8;
          bf16x8 a1 = *(const bf16x8*)&hT[w][p][0][ao];
          bf16x8 a2 = *(const bf16x8*)&hT[w][p][1][ao];
          bf16x8 a3 = *(const bf16x8*)&hT[w][p][2][ao];
#pragma unroll
          for (int nt = 0; nt < 4; ++nt) {
            f32x4 c = acc[nt];
            bf16x8 b1 = wfr[p][kc][nt][0], b2 = wfr[p][kc][nt][1], b3 = wfr[p][kc][nt][2];
            c = __builtin_amdgcn_mfma_f32_16x16x32_bf16(a3, b1, c, 0, 0, 0);
            c = __builtin_amdgcn_mfma_f32_16x16x32_bf16(a2, b2, c, 0, 0, 0);
            c = __builtin_amdgcn_mfma_f32_16x16x32_bf16(a1, b3, c, 0, 0, 0);
            c = __builtin_amdgcn_mfma_f32_16x16x32_bf16(a2, b1, c, 0, 0, 0);
            c = __builtin_amdgcn_mfma_f32_16x16x32_bf16(a1, b2, c, 0, 0, 0);
            c = __builtin_amdgcn_mfma_f32_16x16x32_bf16(a1, b1, c, 0, 0, 0);
            acc[nt] = c;
          }
        }
      }
      // ---- partials -> LDS (C layout: col=li, row=quad*4+r) ----
#pragma unroll
      for (int nt = 0; nt < 4; ++nt)
#pragma unroll
        for (int r = 0; r < 4; ++r) {
          red[w][(quad * 4 + r) * 64 + nt * 16 + li] = acc[nt][r];
        }
      __syncthreads();
    }

    // ---- epilogue: v = relu(xin + sum8(partials)); in-place out; publish ----
    float sx = 0.f, sy = 0.f;
    if (t > 0) {
#pragma unroll
      for (int ww = 0; ww < 8; ++ww) {
        sx += red[ww][eb * 64 + ecp];
        sy += red[ww][eb * 64 + ecp + 1];
      }
    }
    size_t o = (size_t)(b0 + eb) * 1048576 + (size_t)t * 1024 + f0 + ecp;
    float2 xin = *(float2*)&out[o];
    float vx = fmaxf(xin.x + sx, 0.f);
    float vy = fmaxf(xin.y + sy, 0.f);
    *(float2*)&out[o] = make_float2(vx, vy);

    Split3 px = split3(vx), py = split3(vy);
    const uint32 pub = (uint32)((t & 1) * 49152 + g * 24576);  // u32 units
    const uint32 pe = (uint32)(eb * 512 + (f0 + ecp) / 2);
    __hip_atomic_store(&hb32[pub + 0 * 8192 + pe], (uint32)px.a | ((uint32)py.a << 16),
                       __ATOMIC_RELAXED, __HIP_MEMORY_SCOPE_AGENT);
    __hip_atomic_store(&hb32[pub + 1 * 8192 + pe], (uint32)px.b | ((uint32)py.b << 16),
                       __ATOMIC_RELAXED, __HIP_MEMORY_SCOPE_AGENT);
    __hip_atomic_store(&hb32[pub + 2 * 8192 + pe], (uint32)px.c | ((uint32)py.c << 16),
                       __ATOMIC_RELAXED, __HIP_MEMORY_SCOPE_AGENT);
    __syncthreads();  // all publishes drained before the release flag store
    if (tid == 0)
      __hip_atomic_store(&ctr[g * 32 + m], (uint32)(t + 1), __ATOMIC_RELEASE,
                         __HIP_MEMORY_SCOPE_AGENT);
  }
}

// ---------------------------------------------------------------------------
// ws layout: [0,256) flags (memset 0); [256, 256+384K) h ping-pong triples.
// Total ws need: ~385 KB.
// ---------------------------------------------------------------------------
extern "C" void kernel_launch(void* const* d_in, const int* in_sizes, int n_in,
                              void* d_out, int out_size, void* d_ws, size_t ws_size,
                              hipStream_t stream) {
  const float* x   = (const float*)d_in[0];
  const float* win = (const float*)d_in[1];
  const float* bin = (const float*)d_in[2];
  const float* whh = (const float*)d_in[3];
  float* out = (float*)d_out;

  hipMemsetAsync(d_ws, 0, 256, stream);
  gemm6<<<2048, 256, 0, stream>>>(x, win, bin, out);

  static const float* whh_a; static float* out_a; static void* ws_a;
  whh_a = whh; out_a = out; ws_a = d_ws;
  void* args[3] = {(void*)&whh_a, (void*)&out_a, (void*)&ws_a};
  hipLaunchCooperativeKernel(reinterpret_cast<void*>(rnn_scan), dim3(32), dim3(512),
                             args, 0, stream);
}

// Round 9
// 15950.702 us; speedup vs baseline: 1.4196x; 1.4196x over previous
//
#include <hip/hip_runtime.h>

typedef unsigned int   uint32;
typedef unsigned short u16;
typedef unsigned long long u64;
typedef __bf16 bf16x8 __attribute__((ext_vector_type(8)));
typedef u16    ushort8 __attribute__((ext_vector_type(8)));
typedef float  f32x4  __attribute__((ext_vector_type(4)));

// ---------------------------------------------------------------------------
// Exact 3-way bf16 split (truncation): v == bf(a)+bf(b)+bf(c) EXACTLY for all
// normal fp32 (24 mantissa bits = 8+8+8; each subtraction is exact).
// ---------------------------------------------------------------------------
struct Split3 { u16 a, b, c; };
__device__ __forceinline__ Split3 split3(float v) {
  uint32 u  = __float_as_uint(v);
  u16 s1    = (u16)(u >> 16);
  float r1  = v - __uint_as_float(u & 0xFFFF0000u);   // exact
  uint32 u2 = __float_as_uint(r1);
  u16 s2    = (u16)(u2 >> 16);
  float r2  = r1 - __uint_as_float(u2 & 0xFFFF0000u); // exact
  u16 s3    = (u16)(__float_as_uint(r2) >> 16);       // r2 fits bf16 exactly
  return {s1, s2, s3};
}

// ===========================================================================
// K1: xin = x @ W_in + b_in   (M=32768, N=1024, K=1024) in fp32-emulated
// bf16x3 MFMA (6 products). Tile 128x128, BK=32, 256 thr (4 waves), grid 2048.
// ===========================================================================
__global__ __launch_bounds__(256, 2) void gemm6(const float* __restrict__ x,
                                                const float* __restrict__ win,
                                                const float* __restrict__ bin,
                                                float* __restrict__ out) {
  __shared__ u16 As[3][128 * 40];  // [split][m][k], pad 40 -> 2-way banks (free)
  __shared__ u16 Bs[3][128 * 40];  // [split][n][k]
  const int bm = blockIdx.x >> 3, bn = blockIdx.x & 7;
  const int tid = threadIdx.x;
  const int w = tid >> 6, lane = tid & 63, quad = lane >> 4, li = lane & 15;
  const int row0 = bm * 128, col0 = bn * 128;

  f32x4 acc[2][8];
#pragma unroll
  for (int a = 0; a < 2; ++a)
#pragma unroll
    for (int b = 0; b < 8; ++b) acc[a][b] = (f32x4){0.f, 0.f, 0.f, 0.f};

  const int bc = tid & 127;       // B: this thread's local col
  const int bkh = tid >> 7;       // B: k-half (0/1) -> k = bkh*16 + kk

  for (int kb = 0; kb < 32; ++kb) {
    __syncthreads();
    // ---- stage A: 128m x 32k fp32 -> 3 split planes ----
#pragma unroll
    for (int i = 0; i < 4; ++i) {
      int idx = i * 256 + tid;                 // 0..1023 float4s
      int m = idx >> 3, kq = (idx & 7) * 4;
      float4 v = *(const float4*)&x[(size_t)(row0 + m) * 1024 + kb * 32 + kq];
      Split3 s0 = split3(v.x), s1 = split3(v.y), s2 = split3(v.z), s3 = split3(v.w);
      *(uint2*)&As[0][m * 40 + kq] = make_uint2((uint32)s0.a | ((uint32)s1.a << 16),
                                                (uint32)s2.a | ((uint32)s3.a << 16));
      *(uint2*)&As[1][m * 40 + kq] = make_uint2((uint32)s0.b | ((uint32)s1.b << 16),
                                                (uint32)s2.b | ((uint32)s3.b << 16));
      *(uint2*)&As[2][m * 40 + kq] = make_uint2((uint32)s0.c | ((uint32)s1.c << 16),
                                                (uint32)s2.c | ((uint32)s3.c << 16));
    }
    // ---- stage B: 32k x 128n, thread reads 16 k's of one col (coalesced) ----
    {
      u16 t1[16], t2[16], t3[16];
#pragma unroll
      for (int kk = 0; kk < 16; ++kk) {
        float v = win[(size_t)(kb * 32 + bkh * 16 + kk) * 1024 + col0 + bc];
        Split3 s = split3(v);
        t1[kk] = s.a; t2[kk] = s.b; t3[kk] = s.c;
      }
#pragma unroll
      for (int q = 0; q < 4; ++q) {
        int off = bc * 40 + bkh * 16 + q * 4;
        *(uint2*)&Bs[0][off] = make_uint2((uint32)t1[q*4] | ((uint32)t1[q*4+1] << 16),
                                          (uint32)t1[q*4+2] | ((uint32)t1[q*4+3] << 16));
        *(uint2*)&Bs[1][off] = make_uint2((uint32)t2[q*4] | ((uint32)t2[q*4+1] << 16),
                                          (uint32)t2[q*4+2] | ((uint32)t2[q*4+3] << 16));
        *(uint2*)&Bs[2][off] = make_uint2((uint32)t3[q*4] | ((uint32)t3[q*4+1] << 16),
                                          (uint32)t3[q*4+2] | ((uint32)t3[q*4+3] << 16));
      }
    }
    __syncthreads();
    // ---- compute: 2 m-tiles x 8 n-tiles x 6 split-products ----
    bf16x8 af[2][3];
#pragma unroll
    for (int mi = 0; mi < 2; ++mi)
#pragma unroll
      for (int s = 0; s < 3; ++s)
        af[mi][s] = *(const bf16x8*)&As[s][(w * 32 + mi * 16 + li) * 40 + quad * 8];
#pragma unroll
    for (int nf = 0; nf < 8; ++nf) {
      bf16x8 b1 = *(const bf16x8*)&Bs[0][(nf * 16 + li) * 40 + quad * 8];
      bf16x8 b2 = *(const bf16x8*)&Bs[1][(nf * 16 + li) * 40 + quad * 8];
      bf16x8 b3 = *(const bf16x8*)&Bs[2][(nf * 16 + li) * 40 + quad * 8];
#pragma unroll
      for (int mi = 0; mi < 2; ++mi) {
        f32x4 c = acc[mi][nf];
        c = __builtin_amdgcn_mfma_f32_16x16x32_bf16(af[mi][2], b1, c, 0, 0, 0); // a3*b1
        c = __builtin_amdgcn_mfma_f32_16x16x32_bf16(af[mi][1], b2, c, 0, 0, 0); // a2*b2
        c = __builtin_amdgcn_mfma_f32_16x16x32_bf16(af[mi][0], b3, c, 0, 0, 0); // a1*b3
        c = __builtin_amdgcn_mfma_f32_16x16x32_bf16(af[mi][1], b1, c, 0, 0, 0); // a2*b1
        c = __builtin_amdgcn_mfma_f32_16x16x32_bf16(af[mi][0], b2, c, 0, 0, 0); // a1*b2
        c = __builtin_amdgcn_mfma_f32_16x16x32_bf16(af[mi][0], b1, c, 0, 0, 0); // a1*b1
        acc[mi][nf] = c;
      }
    }
  }
  // ---- epilogue: + bias (no relu here; scan applies relu per step) ----
#pragma unroll
  for (int mi = 0; mi < 2; ++mi)
#pragma unroll
    for (int nf = 0; nf < 8; ++nf) {
      int gcol = col0 + nf * 16 + li;
      float bias = bin[gcol];
#pragma unroll
      for (int r = 0; r < 4; ++r) {
        int grow = row0 + w * 32 + mi * 16 + quad * 4 + r;
        out[(size_t)grow * 1024 + gcol] = acc[mi][nf][r] + bias;
      }
    }
}

// ===========================================================================
// K2 v9: persistent recurrence, 32 WGs x 512 thr, FLAGLESS tagged exchange.
// Each h element is published as ONE atomic u64 {tag16=t+1, s3,s2,s1}.
// Consumers poll the DATA with relaxed agent loads until all 32 of their
// words carry tag==t. Validity is in-band (per-word 8B atomicity), so there
// is NO acquire, NO release, NO fence, NO flag, NO pre-publish drain —
// i.e. none of the per-poll L2 invalidates / per-step L2 writebacks that
// the v1-v8 acquire/release protocol paid 1024 times per WG.
//
// FROZEN CORE (do not touch): rolled compute p-loop (#pragma unroll 1) with
// runtime-p-indexed wfr (scratch-resident; static-p register promotion
// MISCOMPILES deterministically — v2-v5, absmax 5.5). MFMA accumulation
// order and split3 numerics identical to v7. xin read stays in epilogue.
//
// LDS: full 1024-k slice staged at once (no two-pass): hTs[3][16][1032] u16
// (pad 8 -> 2-way banks, free) = 96.8 KB + red 32 KB = 131.8 KB.
// Barriers/step: 3. hbuf: [par][team][b][k] u64 = 2 MB (memset at launch;
// tags start 0, first valid tag is 1).
// ===========================================================================
#define WROW2 1032   // 1024 k + 8 pad (u16 units); li-stride = 2064B -> 2-way banks

__global__ __launch_bounds__(512, 1) void rnn_scan(const float* __restrict__ whh,
                                                   float* __restrict__ out,
                                                   void* ws) {
  u64* hb64 = (u64*)((char*)ws + 256);

  const int wg = blockIdx.x, g = wg & 1, m = wg >> 1;   // m in 0..15
  const int tid = threadIdx.x;
  const int w = tid >> 6, lane = tid & 63, quad = lane >> 4, li = lane & 15;
  const int b0 = g * 16, f0 = m * 64;

  __shared__ u16  hTs[3 * 16 * WROW2];   // [split][b][k+pad], 96.75 KB
  __shared__ float red[8][1024];         // per-wave partials [b*64+col], 32 KB

  // ---- W_hh -> 48 B-frags: wfr[p][kc][nt][s]; k = p*512+w*64+kc*32+quad*8+j
  bf16x8 wfr[2][2][4][3];
#pragma unroll
  for (int p = 0; p < 2; ++p)
#pragma unroll
    for (int kc = 0; kc < 2; ++kc)
#pragma unroll
      for (int nt = 0; nt < 4; ++nt) {
        ushort8 t1, t2, t3;
#pragma unroll
        for (int j = 0; j < 8; ++j) {
          float v = whh[(size_t)(p * 512 + w * 64 + kc * 32 + quad * 8 + j) * 1024
                        + f0 + nt * 16 + li];
          Split3 s = split3(v);
          t1[j] = s.a; t2[j] = s.b; t3[j] = s.c;
        }
        wfr[p][kc][nt][0] = __builtin_bit_cast(bf16x8, t1);
        wfr[p][kc][nt][1] = __builtin_bit_cast(bf16x8, t2);
        wfr[p][kc][nt][2] = __builtin_bit_cast(bf16x8, t3);
      }

  // epilogue ownership: thread -> (batch eb, col pair ecp), 512 thr cover 16x64
  const int eb = tid >> 5, ecp = (tid & 31) * 2;

#pragma unroll 1
  for (int t = 0; t < 1024; ++t) {
    f32x4 acc[4];
#pragma unroll
    for (int nt = 0; nt < 4; ++nt) acc[nt] = (f32x4){0.f, 0.f, 0.f, 0.f};

    if (t > 0) {
      const uint32 tagv = (uint32)t;   // h(t-1) was published with tag t
      const size_t base = (size_t)((t - 1) & 1) * 32768 + (size_t)g * 16384;

      // ---- poll+load own slice: thread owns col-pair tid*2 for all 16 b.
      //      32 u64 relaxed atomic loads per pass; retry (per-lane) until
      //      every word's tag matches. No fences anywhere.
      u64 vv[32];
      bool ok = false;
      while (!ok) {
        ok = true;
#pragma unroll
        for (int i = 0; i < 16; ++i) {
          vv[2 * i]     = __hip_atomic_load(&hb64[base + (size_t)i * 1024 + tid * 2],
                                            __ATOMIC_RELAXED, __HIP_MEMORY_SCOPE_AGENT);
          vv[2 * i + 1] = __hip_atomic_load(&hb64[base + (size_t)i * 1024 + tid * 2 + 1],
                                            __ATOMIC_RELAXED, __HIP_MEMORY_SCOPE_AGENT);
        }
#pragma unroll
        for (int i = 0; i < 32; ++i) ok = ok && ((uint32)(vv[i] >> 48) == tagv);
        if (!ok) __builtin_amdgcn_s_sleep(1);
      }
      // ---- extract 3 splits, pack col-pairs, ds_write ----
#pragma unroll
      for (int i = 0; i < 16; ++i) {
        u64 va = vv[2 * i], vb = vv[2 * i + 1];
#pragma unroll
        for (int s = 0; s < 3; ++s) {
          uint32 pk = ((uint32)(va >> (16 * s)) & 0xFFFFu) |
                      (((uint32)(vb >> (16 * s)) & 0xFFFFu) << 16);
          *(uint32*)&hTs[s * 16 * WROW2 + i * WROW2 + tid * 2] = pk;
        }
      }
      __syncthreads();

      // ---- compute: rolled p (FROZEN — wfr must stay runtime-p-indexed) ----
#pragma unroll 1
      for (int p = 0; p < 2; ++p) {
#pragma unroll
        for (int kc = 0; kc < 2; ++kc) {
          const int ko = p * 512 + w * 64 + kc * 32 + quad * 8;
          bf16x8 a1 = *(const bf16x8*)&hTs[0 * 16 * WROW2 + li * WROW2 + ko];
          bf16x8 a2 = *(const bf16x8*)&hTs[1 * 16 * WROW2 + li * WROW2 + ko];
          bf16x8 a3 = *(const bf16x8*)&hTs[2 * 16 * WROW2 + li * WROW2 + ko];
#pragma unroll
          for (int nt = 0; nt < 4; ++nt) {
            f32x4 c = acc[nt];
            bf16x8 b1 = wfr[p][kc][nt][0], b2 = wfr[p][kc][nt][1], b3 = wfr[p][kc][nt][2];
            c = __builtin_amdgcn_mfma_f32_16x16x32_bf16(a3, b1, c, 0, 0, 0);
            c = __builtin_amdgcn_mfma_f32_16x16x32_bf16(a2, b2, c, 0, 0, 0);
            c = __builtin_amdgcn_mfma_f32_16x16x32_bf16(a1, b3, c, 0, 0, 0);
            c = __builtin_amdgcn_mfma_f32_16x16x32_bf16(a2, b1, c, 0, 0, 0);
            c = __builtin_amdgcn_mfma_f32_16x16x32_bf16(a1, b2, c, 0, 0, 0);
            c = __builtin_amdgcn_mfma_f32_16x16x32_bf16(a1, b1, c, 0, 0, 0);
            acc[nt] = c;
          }
        }
      }
      // ---- partials -> LDS (C layout: col=li, row=quad*4+r) ----
#pragma unroll
      for (int nt = 0; nt < 4; ++nt)
#pragma unroll
        for (int r = 0; r < 4; ++r) {
          red[w][(quad * 4 + r) * 64 + nt * 16 + li] = acc[nt][r];
        }
      __syncthreads();
    }

    // ---- epilogue: v = relu(xin + sum8(partials)); in-place out; publish ----
    float sx = 0.f, sy = 0.f;
    if (t > 0) {
#pragma unroll
      for (int ww = 0; ww < 8; ++ww) {
        sx += red[ww][eb * 64 + ecp];
        sy += red[ww][eb * 64 + ecp + 1];
      }
    }
    size_t o = (size_t)(b0 + eb) * 1048576 + (size_t)t * 1024 + f0 + ecp;
    float2 xin = *(float2*)&out[o];
    float vx = fmaxf(xin.x + sx, 0.f);
    float vy = fmaxf(xin.y + sy, 0.f);
    *(float2*)&out[o] = make_float2(vx, vy);

    // ---- publish h(t): 2 self-validating u64 {tag=t+1, s3,s2,s1} ----
    Split3 px = split3(vx), py = split3(vy);
    const u64 tag = (u64)(uint32)(t + 1) << 48;
    u64 w0 = (u64)px.a | ((u64)px.b << 16) | ((u64)px.c << 32) | tag;
    u64 w1 = (u64)py.a | ((u64)py.b << 16) | ((u64)py.c << 32) | tag;
    const size_t pbase = (size_t)(t & 1) * 32768 + (size_t)g * 16384
                       + (size_t)eb * 1024 + (f0 + ecp);
    __hip_atomic_store(&hb64[pbase],     w0, __ATOMIC_RELAXED, __HIP_MEMORY_SCOPE_AGENT);
    __hip_atomic_store(&hb64[pbase + 1], w1, __ATOMIC_RELAXED, __HIP_MEMORY_SCOPE_AGENT);

    __syncthreads();  // protect red[] (next step's write vs this step's reads)
  }
}

// ---------------------------------------------------------------------------
// ws layout: [0,256) unused (kept for alignment); [256, 256+2MB) tagged h
// ping-pong: [par][team][b][k] u64. Memset 0 at launch (tag 0 never valid).
// Total ws need: ~2.1 MB.
// ---------------------------------------------------------------------------
extern "C" void kernel_launch(void* const* d_in, const int* in_sizes, int n_in,
                              void* d_out, int out_size, void* d_ws, size_t ws_size,
                              hipStream_t stream) {
  const float* x   = (const float*)d_in[0];
  const float* win = (const float*)d_in[1];
  const float* bin = (const float*)d_in[2];
  const float* whh = (const float*)d_in[3];
  float* out = (float*)d_out;

  hipMemsetAsync(d_ws, 0, 256 + (size_t)2 * 1024 * 1024, stream);
  gemm6<<<2048, 256, 0, stream>>>(x, win, bin, out);

  static const float* whh_a; static float* out_a; static void* ws_a;
  whh_a = whh; out_a = out; ws_a = d_ws;
  void* args[3] = {(void*)&whh_a, (void*)&out_a, (void*)&ws_a};
  hipLaunchCooperativeKernel(reinterpret_cast<void*>(rnn_scan), dim3(32), dim3(512),
                             args, 0, stream);
}

// Round 10
// 15498.785 us; speedup vs baseline: 1.4610x; 1.0292x over previous
//
#include <hip/hip_runtime.h>

typedef unsigned int   uint32;
typedef unsigned short u16;
typedef unsigned long long u64;
typedef __bf16 bf16x8 __attribute__((ext_vector_type(8)));
typedef u16    ushort8 __attribute__((ext_vector_type(8)));
typedef float  f32x4  __attribute__((ext_vector_type(4)));

// ---------------------------------------------------------------------------
// Exact 3-way bf16 split (truncation): v == bf(a)+bf(b)+bf(c) EXACTLY for all
// normal fp32 (24 mantissa bits = 8+8+8; each subtraction is exact).
// ---------------------------------------------------------------------------
struct Split3 { u16 a, b, c; };
__device__ __forceinline__ Split3 split3(float v) {
  uint32 u  = __float_as_uint(v);
  u16 s1    = (u16)(u >> 16);
  float r1  = v - __uint_as_float(u & 0xFFFF0000u);   // exact
  uint32 u2 = __float_as_uint(r1);
  u16 s2    = (u16)(u2 >> 16);
  float r2  = r1 - __uint_as_float(u2 & 0xFFFF0000u); // exact
  u16 s3    = (u16)(__float_as_uint(r2) >> 16);       // r2 fits bf16 exactly
  return {s1, s2, s3};
}

// ===========================================================================
// K1: xin = x @ W_in + b_in   (M=32768, N=1024, K=1024) in fp32-emulated
// bf16x3 MFMA (6 products). Tile 128x128, BK=32, 256 thr (4 waves), grid 2048.
// ===========================================================================
__global__ __launch_bounds__(256, 2) void gemm6(const float* __restrict__ x,
                                                const float* __restrict__ win,
                                                const float* __restrict__ bin,
                                                float* __restrict__ out) {
  __shared__ u16 As[3][128 * 40];  // [split][m][k], pad 40 -> 2-way banks (free)
  __shared__ u16 Bs[3][128 * 40];  // [split][n][k]
  const int bm = blockIdx.x >> 3, bn = blockIdx.x & 7;
  const int tid = threadIdx.x;
  const int w = tid >> 6, lane = tid & 63, quad = lane >> 4, li = lane & 15;
  const int row0 = bm * 128, col0 = bn * 128;

  f32x4 acc[2][8];
#pragma unroll
  for (int a = 0; a < 2; ++a)
#pragma unroll
    for (int b = 0; b < 8; ++b) acc[a][b] = (f32x4){0.f, 0.f, 0.f, 0.f};

  const int bc = tid & 127;       // B: this thread's local col
  const int bkh = tid >> 7;       // B: k-half (0/1) -> k = bkh*16 + kk

  for (int kb = 0; kb < 32; ++kb) {
    __syncthreads();
    // ---- stage A: 128m x 32k fp32 -> 3 split planes ----
#pragma unroll
    for (int i = 0; i < 4; ++i) {
      int idx = i * 256 + tid;                 // 0..1023 float4s
      int m = idx >> 3, kq = (idx & 7) * 4;
      float4 v = *(const float4*)&x[(size_t)(row0 + m) * 1024 + kb * 32 + kq];
      Split3 s0 = split3(v.x), s1 = split3(v.y), s2 = split3(v.z), s3 = split3(v.w);
      *(uint2*)&As[0][m * 40 + kq] = make_uint2((uint32)s0.a | ((uint32)s1.a << 16),
                                                (uint32)s2.a | ((uint32)s3.a << 16));
      *(uint2*)&As[1][m * 40 + kq] = make_uint2((uint32)s0.b | ((uint32)s1.b << 16),
                                                (uint32)s2.b | ((uint32)s3.b << 16));
      *(uint2*)&As[2][m * 40 + kq] = make_uint2((uint32)s0.c | ((uint32)s1.c << 16),
                                                (uint32)s2.c | ((uint32)s3.c << 16));
    }
    // ---- stage B: 32k x 128n, thread reads 16 k's of one col (coalesced) ----
    {
      u16 t1[16], t2[16], t3[16];
#pragma unroll
      for (int kk = 0; kk < 16; ++kk) {
        float v = win[(size_t)(kb * 32 + bkh * 16 + kk) * 1024 + col0 + bc];
        Split3 s = split3(v);
        t1[kk] = s.a; t2[kk] = s.b; t3[kk] = s.c;
      }
#pragma unroll
      for (int q = 0; q < 4; ++q) {
        int off = bc * 40 + bkh * 16 + q * 4;
        *(uint2*)&Bs[0][off] = make_uint2((uint32)t1[q*4] | ((uint32)t1[q*4+1] << 16),
                                          (uint32)t1[q*4+2] | ((uint32)t1[q*4+3] << 16));
        *(uint2*)&Bs[1][off] = make_uint2((uint32)t2[q*4] | ((uint32)t2[q*4+1] << 16),
                                          (uint32)t2[q*4+2] | ((uint32)t2[q*4+3] << 16));
        *(uint2*)&Bs[2][off] = make_uint2((uint32)t3[q*4] | ((uint32)t3[q*4+1] << 16),
                                          (uint32)t3[q*4+2] | ((uint32)t3[q*4+3] << 16));
      }
    }
    __syncthreads();
    // ---- compute: 2 m-tiles x 8 n-tiles x 6 split-products ----
    bf16x8 af[2][3];
#pragma unroll
    for (int mi = 0; mi < 2; ++mi)
#pragma unroll
      for (int s = 0; s < 3; ++s)
        af[mi][s] = *(const bf16x8*)&As[s][(w * 32 + mi * 16 + li) * 40 + quad * 8];
#pragma unroll
    for (int nf = 0; nf < 8; ++nf) {
      bf16x8 b1 = *(const bf16x8*)&Bs[0][(nf * 16 + li) * 40 + quad * 8];
      bf16x8 b2 = *(const bf16x8*)&Bs[1][(nf * 16 + li) * 40 + quad * 8];
      bf16x8 b3 = *(const bf16x8*)&Bs[2][(nf * 16 + li) * 40 + quad * 8];
#pragma unroll
      for (int mi = 0; mi < 2; ++mi) {
        f32x4 c = acc[mi][nf];
        c = __builtin_amdgcn_mfma_f32_16x16x32_bf16(af[mi][2], b1, c, 0, 0, 0); // a3*b1
        c = __builtin_amdgcn_mfma_f32_16x16x32_bf16(af[mi][1], b2, c, 0, 0, 0); // a2*b2
        c = __builtin_amdgcn_mfma_f32_16x16x32_bf16(af[mi][0], b3, c, 0, 0, 0); // a1*b3
        c = __builtin_amdgcn_mfma_f32_16x16x32_bf16(af[mi][1], b1, c, 0, 0, 0); // a2*b1
        c = __builtin_amdgcn_mfma_f32_16x16x32_bf16(af[mi][0], b2, c, 0, 0, 0); // a1*b2
        c = __builtin_amdgcn_mfma_f32_16x16x32_bf16(af[mi][0], b1, c, 0, 0, 0); // a1*b1
        acc[mi][nf] = c;
      }
    }
  }
  // ---- epilogue: + bias (no relu here; scan applies relu per step) ----
#pragma unroll
  for (int mi = 0; mi < 2; ++mi)
#pragma unroll
    for (int nf = 0; nf < 8; ++nf) {
      int gcol = col0 + nf * 16 + li;
      float bias = bin[gcol];
#pragma unroll
      for (int r = 0; r < 4; ++r) {
        int grow = row0 + w * 32 + mi * 16 + quad * 4 + r;
        out[(size_t)grow * 1024 + gcol] = acc[mi][nf][r] + bias;
      }
    }
}

// ===========================================================================
// K2 v10: persistent recurrence, 32 WGs x 512 thr, flagless tagged exchange
// (v9, proven: each h element is one atomic u64 {tag16=t+1, s3,s2,s1};
// consumers poll the data itself with relaxed agent loads; no acquire/
// release/fence/flag anywhere).
//
// v10 changes vs v9 (poll traffic + serial tail):
//  - STRAGGLER-ONLY RETRY: 32-bit valid mask; each retry flight reloads only
//    words whose tag was stale (v9 reloaded all 32 -> 16K threads x 32 u64
//    per flight congested the fabric against the publishes themselves;
//    FETCH_SIZE 603 MB showed it). Values consumed are identical.
//  - xin PREFETCH above the poll: out-row t has a single writer (this
//    thread, later this step) and is hbuf-independent -> value identical;
//    removes ~1us of load latency from the post-barrier serial tail.
//  - PUBLISH BEFORE OUT-STORE: the two epilogue stores are independent;
//    publishing first unblocks consumers earlier.
//
// FROZEN CORE (do not touch): rolled compute p-loop (#pragma unroll 1) with
// runtime-p-indexed wfr (scratch-resident; static-p register promotion
// MISCOMPILES deterministically — v2-v5, absmax 5.5). MFMA accumulation
// order and split3 numerics identical.
// ===========================================================================
#define WROW2 1032   // 1024 k + 8 pad (u16 units); li-stride = 2064B -> 2-way banks

__global__ __launch_bounds__(512, 1) void rnn_scan(const float* __restrict__ whh,
                                                   float* __restrict__ out,
                                                   void* ws) {
  u64* hb64 = (u64*)((char*)ws + 256);

  const int wg = blockIdx.x, g = wg & 1, m = wg >> 1;   // m in 0..15
  const int tid = threadIdx.x;
  const int w = tid >> 6, lane = tid & 63, quad = lane >> 4, li = lane & 15;
  const int b0 = g * 16, f0 = m * 64;

  __shared__ u16  hTs[3 * 16 * WROW2];   // [split][b][k+pad], 96.75 KB
  __shared__ float red[8][1024];         // per-wave partials [b*64+col], 32 KB

  // ---- W_hh -> 48 B-frags: wfr[p][kc][nt][s]; k = p*512+w*64+kc*32+quad*8+j
  bf16x8 wfr[2][2][4][3];
#pragma unroll
  for (int p = 0; p < 2; ++p)
#pragma unroll
    for (int kc = 0; kc < 2; ++kc)
#pragma unroll
      for (int nt = 0; nt < 4; ++nt) {
        ushort8 t1, t2, t3;
#pragma unroll
        for (int j = 0; j < 8; ++j) {
          float v = whh[(size_t)(p * 512 + w * 64 + kc * 32 + quad * 8 + j) * 1024
                        + f0 + nt * 16 + li];
          Split3 s = split3(v);
          t1[j] = s.a; t2[j] = s.b; t3[j] = s.c;
        }
        wfr[p][kc][nt][0] = __builtin_bit_cast(bf16x8, t1);
        wfr[p][kc][nt][1] = __builtin_bit_cast(bf16x8, t2);
        wfr[p][kc][nt][2] = __builtin_bit_cast(bf16x8, t3);
      }

  // epilogue ownership: thread -> (batch eb, col pair ecp), 512 thr cover 16x64
  const int eb = tid >> 5, ecp = (tid & 31) * 2;

#pragma unroll 1
  for (int t = 0; t < 1024; ++t) {
    f32x4 acc[4];
#pragma unroll
    for (int nt = 0; nt < 4; ++nt) acc[nt] = (f32x4){0.f, 0.f, 0.f, 0.f};

    // xin prefetch: out-row t has a single writer (this thread, this step);
    // independent of hbuf -> safe to read before the poll, hides its latency.
    const size_t o = (size_t)(b0 + eb) * 1048576 + (size_t)t * 1024 + f0 + ecp;
    const float2 xin = *(const float2*)&out[o];

    if (t > 0) {
      const uint32 tagv = (uint32)t;   // h(t-1) was published with tag t
      const size_t base = (size_t)((t - 1) & 1) * 32768 + (size_t)g * 16384;

      // ---- poll+load own slice: thread owns col-pair tid*2 for all 16 b.
      //      Straggler-only retry: reload just the words whose tag is stale.
      u64 vv[32];
      uint32 inval = 0xFFFFFFFFu;      // bit i: word i not yet valid
      while (inval) {
#pragma unroll
        for (int i = 0; i < 32; ++i) {
          if (inval & (1u << i)) {
            vv[i] = __hip_atomic_load(
                &hb64[base + (size_t)(i >> 1) * 1024 + tid * 2 + (i & 1)],
                __ATOMIC_RELAXED, __HIP_MEMORY_SCOPE_AGENT);
          }
        }
#pragma unroll
        for (int i = 0; i < 32; ++i)
          if ((uint32)(vv[i] >> 48) == tagv) inval &= ~(1u << i);
        if (inval) __builtin_amdgcn_s_sleep(1);
      }
      // ---- extract 3 splits, pack col-pairs, ds_write ----
#pragma unroll
      for (int i = 0; i < 16; ++i) {
        u64 va = vv[2 * i], vb = vv[2 * i + 1];
#pragma unroll
        for (int s = 0; s < 3; ++s) {
          uint32 pk = ((uint32)(va >> (16 * s)) & 0xFFFFu) |
                      (((uint32)(vb >> (16 * s)) & 0xFFFFu) << 16);
          *(uint32*)&hTs[s * 16 * WROW2 + i * WROW2 + tid * 2] = pk;
        }
      }
      __syncthreads();

      // ---- compute: rolled p (FROZEN — wfr must stay runtime-p-indexed) ----
#pragma unroll 1
      for (int p = 0; p < 2; ++p) {
#pragma unroll
        for (int kc = 0; kc < 2; ++kc) {
          const int ko = p * 512 + w * 64 + kc * 32 + quad * 8;
          bf16x8 a1 = *(const bf16x8*)&hTs[0 * 16 * WROW2 + li * WROW2 + ko];
          bf16x8 a2 = *(const bf16x8*)&hTs[1 * 16 * WROW2 + li * WROW2 + ko];
          bf16x8 a3 = *(const bf16x8*)&hTs[2 * 16 * WROW2 + li * WROW2 + ko];
#pragma unroll
          for (int nt = 0; nt < 4; ++nt) {
            f32x4 c = acc[nt];
            bf16x8 b1 = wfr[p][kc][nt][0], b2 = wfr[p][kc][nt][1], b3 = wfr[p][kc][nt][2];
            c = __builtin_amdgcn_mfma_f32_16x16x32_bf16(a3, b1, c, 0, 0, 0);
            c = __builtin_amdgcn_mfma_f32_16x16x32_bf16(a2, b2, c, 0, 0, 0);
            c = __builtin_amdgcn_mfma_f32_16x16x32_bf16(a1, b3, c, 0, 0, 0);
            c = __builtin_amdgcn_mfma_f32_16x16x32_bf16(a2, b1, c, 0, 0, 0);
            c = __builtin_amdgcn_mfma_f32_16x16x32_bf16(a1, b2, c, 0, 0, 0);
            c = __builtin_amdgcn_mfma_f32_16x16x32_bf16(a1, b1, c, 0, 0, 0);
            acc[nt] = c;
          }
        }
      }
      // ---- partials -> LDS (C layout: col=li, row=quad*4+r) ----
#pragma unroll
      for (int nt = 0; nt < 4; ++nt)
#pragma unroll
        for (int r = 0; r < 4; ++r) {
          red[w][(quad * 4 + r) * 64 + nt * 16 + li] = acc[nt][r];
        }
      __syncthreads();
    }

    // ---- epilogue: v = relu(xin + sum8(partials)); publish FIRST; out ----
    float sx = 0.f, sy = 0.f;
    if (t > 0) {
#pragma unroll
      for (int ww = 0; ww < 8; ++ww) {
        sx += red[ww][eb * 64 + ecp];
        sy += red[ww][eb * 64 + ecp + 1];
      }
    }
    float vx = fmaxf(xin.x + sx, 0.f);
    float vy = fmaxf(xin.y + sy, 0.f);

    // publish h(t) first: 2 self-validating u64 {tag=t+1, s3,s2,s1}
    Split3 px = split3(vx), py = split3(vy);
    const u64 tag = (u64)(uint32)(t + 1) << 48;
    u64 w0 = (u64)px.a | ((u64)px.b << 16) | ((u64)px.c << 32) | tag;
    u64 w1 = (u64)py.a | ((u64)py.b << 16) | ((u64)py.c << 32) | tag;
    const size_t pbase = (size_t)(t & 1) * 32768 + (size_t)g * 16384
                       + (size_t)eb * 1024 + (f0 + ecp);
    __hip_atomic_store(&hb64[pbase],     w0, __ATOMIC_RELAXED, __HIP_MEMORY_SCOPE_AGENT);
    __hip_atomic_store(&hb64[pbase + 1], w1, __ATOMIC_RELAXED, __HIP_MEMORY_SCOPE_AGENT);

    // then the (independent) output store
    *(float2*)&out[o] = make_float2(vx, vy);

    __syncthreads();  // protect red[] (next step's write vs this step's reads)
  }
}

// ---------------------------------------------------------------------------
// ws layout: [0,256) unused (kept for alignment); [256, 256+2MB) tagged h
// ping-pong: [par][team][b][k] u64. Memset 0 at launch (tag 0 never valid).
// Total ws need: ~2.1 MB.
// ---------------------------------------------------------------------------
extern "C" void kernel_launch(void* const* d_in, const int* in_sizes, int n_in,
                              void* d_out, int out_size, void* d_ws, size_t ws_size,
                              hipStream_t stream) {
  const float* x   = (const float*)d_in[0];
  const float* win = (const float*)d_in[1];
  const float* bin = (const float*)d_in[2];
  const float* whh = (const float*)d_in[3];
  float* out = (float*)d_out;

  hipMemsetAsync(d_ws, 0, 256 + (size_t)2 * 1024 * 1024, stream);
  gemm6<<<2048, 256, 0, stream>>>(x, win, bin, out);

  static const float* whh_a; static float* out_a; static void* ws_a;
  whh_a = whh; out_a = out; ws_a = d_ws;
  void* args[3] = {(void*)&whh_a, (void*)&out_a, (void*)&ws_a};
  hipLaunchCooperativeKernel(reinterpret_cast<void*>(rnn_scan), dim3(32), dim3(512),
                             args, 0, stream);
}